// Round 10
// baseline (250.282 us; speedup 1.0000x reference)
//
#include <hip/hip_runtime.h>
#include <hip/hip_bf16.h>

// ---------------- problem constants ----------------
#define HW    4096      // H*W
#define BB    8         // batch
#define TT    8         // time steps

typedef _Float16 halfx8 __attribute__((ext_vector_type(8)));
typedef float    floatx4 __attribute__((ext_vector_type(4)));
typedef float    floatx2 __attribute__((ext_vector_type(2)));

__device__ inline float fast_exp2(float x) {
#if __has_builtin(__builtin_amdgcn_exp2f)
    return __builtin_amdgcn_exp2f(x);
#else
    return __builtin_exp2f(x);
#endif
}
__device__ inline float fast_rcp(float x) {
#if __has_builtin(__builtin_amdgcn_rcpf)
    return __builtin_amdgcn_rcpf(x);
#else
    return 1.0f / x;
#endif
}
__device__ inline floatx2 exp2x2(floatx2 x) {
    floatx2 r; r.x = fast_exp2(x.x); r.y = fast_exp2(x.y); return r;
}
__device__ inline floatx2 rcpx2(floatx2 x) {
    floatx2 r; r.x = fast_rcp(x.x); r.y = fast_rcp(x.y); return r;
}

union pack8 { _Float16 h[8]; uint4 u; };

// ---------------- single fused kernel: conv_in + LSTM + conv_out ----------------
// Block = 512 threads = 8 waves = ONE 16-pixel tile x ALL 8 groups (wave wv ==
// group g). Block self-contained: repacks w_hh -> f16 MFMA B-fragments into its
// own LDS (w_hh is L2-resident; ~64KB L2 reads/block), builds wxb / s-proj
// frags inline -> no prep kernel, no workspace, one launch.
// t-loop structure is r7's proven 52-VGPR recipe: asm memory barrier keeps
// B-frags in LDS (2 blocks/CU, 16 waves/CU). Activations use the batched
// packed-reciprocal (rcp insts 80->24 per lane-step; trans pipe is ~half of
// VALU busy). wxb stays in LDS (r8: wxb-in-regs crossed the unified VGPR+AGPR
// 4-waves/SIMD cliff). w_in/w_out staged with row stride 65 (== 1 mod 32) to
// kill the 8-way same-bank conflicts of the stride-64 layout (r9: 3.28M).
// LDS = 80128 B <= 81920 -> 2 blocks/CU. NO forced min-waves bound (r2/r3).
__global__ __launch_bounds__(512) void lstm_kernel(
    const float* __restrict__ hin,    // (B, 64, HW)
    const float* __restrict__ w_in,   // (64, 64)
    const float* __restrict__ b_in,   // (64,)
    const float* __restrict__ w_ih,   // (256, 1)
    const float* __restrict__ w_hh,   // (256, 64)
    const float* __restrict__ b_ih,   // (256,)
    const float* __restrict__ b_hh,   // (256,)
    const float* __restrict__ w_s,    // (1, 64)
    const float* __restrict__ b_s_p,  // (1,)
    const float* __restrict__ w_out,  // (64, 64)
    const float* __restrict__ b_out,  // (64,)
    float* __restrict__ out) {        // (B, 64, HW)
    __shared__ uint4 wfrag_lds[2176];                  // 34816 B: 32 w_hh + 2 w_s frags
    __shared__ floatx2 wxb_lds[256];                   // 2048 B: per-gate {w_x, bias}
    __shared__ __align__(16) float x_lds[1024];        // 4096 B: [g][t][px16]
    __shared__ __align__(16) _Float16 h_lds[9216];     // 18432 B: 8 waves x 16 x 72
    __shared__ __align__(16) float stile[1024];        // 4096 B: [c64][px16]; hin staging then s
    __shared__ float wt_lds[4160];                     // 16640 B: 64 rows x stride 65 (w_in then w_out)

    int tid = threadIdx.x;
    int ptile = blockIdx.x & 255;         // 256 tiles of 16 px
    int b     = blockIdx.x >> 8;
    int p0 = ptile * 16;

    int lane = tid & 63;
    int wv   = tid >> 6;                  // 0..7 == group g
    int g    = wv;
    int s    = lane & 15;                 // pixel-local == MFMA seq
    int q    = lane >> 4;

    // ---- repack w_hh -> B-fragment-ordered f16 (frag fi=nb*2+kc, entry e=fi*64+l;
    //      lane l holds B[k=kc*32+(l>>4)*8+j][n=(l&15)] = w_hh[gate=(l&15)+16nb][hid=k])
    #pragma unroll
    for (int i = 0; i < 4; ++i) {
        int e  = tid + 512 * i;           // 0..2047
        int l  = e & 63;
        int fi = e >> 6;
        int nb = fi >> 1, kc = fi & 1;
        int gate = (l & 15) + 16 * nb;
        int hid  = kc * 32 + (l >> 4) * 8;
        const floatx4* src = (const floatx4*)&w_hh[gate * 64 + hid];
        floatx4 v0 = src[0], v1 = src[1];
        pack8 p;
        p.h[0] = (_Float16)v0[0]; p.h[1] = (_Float16)v0[1];
        p.h[2] = (_Float16)v0[2]; p.h[3] = (_Float16)v0[3];
        p.h[4] = (_Float16)v1[0]; p.h[5] = (_Float16)v1[1];
        p.h[6] = (_Float16)v1[2]; p.h[7] = (_Float16)v1[3];
        wfrag_lds[e] = p.u;
    }
    // s-projection fragments (entries 2048..2175): B[k][0] = w_s[k], other cols 0
    if (tid < 128) {
        int l = tid & 63, kc = tid >> 6;
        pack8 p;
        #pragma unroll
        for (int j = 0; j < 8; ++j) p.h[j] = (_Float16)0.0f;
        if ((l & 15) == 0) {
            #pragma unroll
            for (int j = 0; j < 8; ++j)
                p.h[j] = (_Float16)w_s[kc * 32 + (l >> 4) * 8 + j];
        }
        wfrag_lds[2048 + kc * 64 + l] = p.u;
    }
    // per-gate {w_x, bias}
    if (tid < 256) {
        floatx2 v; v.x = w_ih[tid]; v.y = b_ih[tid] + b_hh[tid];
        wxb_lds[tid] = v;
    }
    // stage w_in rows with stride 65 (bank-spread)
    #pragma unroll
    for (int i = 0; i < 8; ++i) {
        int idx = tid + 512 * i;          // 0..4095
        wt_lds[(idx >> 6) * 65 + (idx & 63)] = w_in[idx];
    }
    // stage hin tile (64 ch x 16 px)
    if (tid < 256) {
        int cc = tid >> 2, f4 = tid & 3;
        ((floatx4*)stile)[tid] = *(const floatx4*)&hin[(b * 64 + cc) * HW + p0 + f4 * 4];
    }
    __syncthreads();

    // ---- conv_in (per wave, own group): x[g][t][px] = sum_c w_in[g8+t][c]*hin[c][px] + b_in
    {
        floatx2 xacc; xacc.x = b_in[g * 8 + q]; xacc.y = b_in[g * 8 + q + 4];
        #pragma unroll 8
        for (int cc = 0; cc < 64; ++cc) {
            float hv = stile[cc * 16 + s];
            floatx2 w;
            w.x = wt_lds[(g * 8 + q) * 65 + cc];
            w.y = wt_lds[(g * 8 + q + 4) * 65 + cc];
            floatx2 h2; h2.x = hv; h2.y = hv;
            xacc = xacc + w * h2;
        }
        x_lds[g * 128 + q * 16 + s]       = xacc.x;
        x_lds[g * 128 + (q + 4) * 16 + s] = xacc.y;
    }
    // zero h state (4608 u32)
    #pragma unroll
    for (int i = 0; i < 9; ++i)
        ((unsigned*)h_lds)[tid + 512 * i] = 0u;
    __syncthreads();   // hin/w_in reads + x/h writes complete

    // stage w_out (raw [o][c], stride 65) for the epilogue; reads happen after
    // the post-t-loop barrier, writes here race nothing (w_in reads done above)
    #pragma unroll
    for (int i = 0; i < 8; ++i) {
        int idx = tid + 512 * i;
        wt_lds[(idx >> 6) * 65 + (idx & 63)] = w_out[idx];
    }

    _Float16* hrow = h_lds + wv * 16 * 72;
    float bs = b_s_p[0];

    const float KS = -1.44269504088896f;  // sigmoid: 1/(1+2^(KS*x))
    const float KT =  2.88539008177793f;  // tanh: 1 - 2/(2^(KT*x)+1)

    float c_st[4][4];
    #pragma unroll
    for (int hb = 0; hb < 4; ++hb)
        #pragma unroll
        for (int r = 0; r < 4; ++r) c_st[hb][r] = 0.0f;

    for (int t = 0; t < TT; ++t) {
        // Hard memory barrier: forbids caching LDS B-frags in registers
        // across iterations (r7: this is what keeps VGPR low -> 16 waves/CU).
        asm volatile("" ::: "memory");

        halfx8 a0 = *(const halfx8*)(hrow + s * 72 + q * 8);        // k = 0..31
        halfx8 a1 = *(const halfx8*)(hrow + s * 72 + q * 8 + 32);   // k = 32..63

        // s_{t-1} = h_t @ w_s via MFMA (col 0 only); lanes s==0 hold seq q*4+r
        if (t > 0) {
            halfx8 sb0 = *(const halfx8*)&wfrag_lds[2048 + lane];
            halfx8 sb1 = *(const halfx8*)&wfrag_lds[2112 + lane];
            floatx4 sa = {0.f, 0.f, 0.f, 0.f};
            sa = __builtin_amdgcn_mfma_f32_16x16x32_f16(a0, sb0, sa, 0, 0, 0);
            sa = __builtin_amdgcn_mfma_f32_16x16x32_f16(a1, sb1, sa, 0, 0, 0);
            if (s == 0) {
                floatx4 o4 = {sa[0] + bs, sa[1] + bs, sa[2] + bs, sa[3] + bs};
                *(floatx4*)&stile[(g * 8 + (t - 1)) * 16 + q * 4] = o4;
            }
        }

        floatx4 xv = *(const floatx4*)&x_lds[g * 128 + t * 16 + q * 4];
        floatx2 xlo; xlo.x = xv[0]; xlo.y = xv[1];
        floatx2 xhi; xhi.x = xv[2]; xhi.y = xv[3];

        #pragma unroll
        for (int hb = 0; hb < 4; ++hb) {
            floatx4 acc[4];
            #pragma unroll
            for (int gi = 0; gi < 4; ++gi) {
                int nb = hb + 4 * gi;
                floatx2 wb = wxb_lds[s + 16 * nb];
                floatx2 lo = xlo * wb.x + wb.y;     // x*w_x + bias as C init (pk_fma)
                floatx2 hi = xhi * wb.x + wb.y;
                floatx4 a = {lo.x, lo.y, hi.x, hi.y};
                halfx8 b0 = *(const halfx8*)&wfrag_lds[(nb * 2 + 0) * 64 + lane];
                halfx8 b1 = *(const halfx8*)&wfrag_lds[(nb * 2 + 1) * 64 + lane];
                a = __builtin_amdgcn_mfma_f32_16x16x32_f16(a0, b0, a, 0, 0, 0);
                a = __builtin_amdgcn_mfma_f32_16x16x32_f16(a1, b1, a, 0, 0, 0);
                acc[gi] = a;
            }
            // ---- activations: batched packed reciprocals (r5/r8-verified math)
            #define ACCP(gi, p) (floatx2{acc[gi][2*(p)], acc[gi][2*(p)+1]})
            // group 1: i (sigmoid), f (sigmoid)
            floatx2 dI0 = exp2x2(ACCP(0,0) * KS) + 1.0f;
            floatx2 dI1 = exp2x2(ACCP(0,1) * KS) + 1.0f;
            floatx2 dF0 = exp2x2(ACCP(1,0) * KS) + 1.0f;
            floatx2 dF1 = exp2x2(ACCP(1,1) * KS) + 1.0f;
            floatx2 q1 = dI0 * dI1, q2 = q1 * dF0, q3 = q2 * dF1;
            floatx2 R  = rcpx2(q3);
            floatx2 fg1 = R * q2;  R = R * dF1;
            floatx2 fg0 = R * q1;  R = R * dF0;
            floatx2 ig1 = R * dI0;
            floatx2 ig0 = R * dI1;
            // group 2: g (tanh), o (sigmoid)
            floatx2 dG0 = exp2x2(ACCP(2,0) * KT) + 1.0f;
            floatx2 dG1 = exp2x2(ACCP(2,1) * KT) + 1.0f;
            floatx2 dO0 = exp2x2(ACCP(3,0) * KS) + 1.0f;
            floatx2 dO1 = exp2x2(ACCP(3,1) * KS) + 1.0f;
            q1 = dG0 * dG1; q2 = q1 * dO0; q3 = q2 * dO1;
            R  = rcpx2(q3);
            floatx2 og1 = R * q2;  R = R * dO1;
            floatx2 og0 = R * q1;  R = R * dO0;
            floatx2 gv1 = (R * dG0) * -2.0f + 1.0f;   // tanh(g) pair1
            floatx2 gv0 = (R * dG1) * -2.0f + 1.0f;   // tanh(g) pair0
            // cell update
            floatx2 cp0; cp0.x = c_st[hb][0]; cp0.y = c_st[hb][1];
            floatx2 cp1; cp1.x = c_st[hb][2]; cp1.y = c_st[hb][3];
            floatx2 c0 = fg0 * cp0 + ig0 * gv0;
            floatx2 c1 = fg1 * cp1 + ig1 * gv1;
            c_st[hb][0] = c0.x; c_st[hb][1] = c0.y;
            c_st[hb][2] = c1.x; c_st[hb][3] = c1.y;
            // tanh(c), batched
            floatx2 dc0 = exp2x2(c0 * KT) + 1.0f;
            floatx2 dc1 = exp2x2(c1 * KT) + 1.0f;
            floatx2 qc = dc0 * dc1;
            floatx2 Rc = rcpx2(qc);
            floatx2 h1 = og1 * ((Rc * dc0) * -2.0f + 1.0f);
            floatx2 h0 = og0 * ((Rc * dc1) * -2.0f + 1.0f);
            // store h (f16) for t+1
            _Float16* wp = hrow + (q * 4) * 72 + s + 16 * hb;
            wp[0 * 72] = (_Float16)h0.x;
            wp[1 * 72] = (_Float16)h0.y;
            wp[2 * 72] = (_Float16)h1.x;
            wp[3 * 72] = (_Float16)h1.y;
            #undef ACCP
        }
    }
    // final s_7 from h_8
    {
        asm volatile("" ::: "memory");
        halfx8 a0 = *(const halfx8*)(hrow + s * 72 + q * 8);
        halfx8 a1 = *(const halfx8*)(hrow + s * 72 + q * 8 + 32);
        halfx8 sb0 = *(const halfx8*)&wfrag_lds[2048 + lane];
        halfx8 sb1 = *(const halfx8*)&wfrag_lds[2112 + lane];
        floatx4 sa = {0.f, 0.f, 0.f, 0.f};
        sa = __builtin_amdgcn_mfma_f32_16x16x32_f16(a0, sb0, sa, 0, 0, 0);
        sa = __builtin_amdgcn_mfma_f32_16x16x32_f16(a1, sb1, sa, 0, 0, 0);
        if (s == 0) {
            floatx4 o4 = {sa[0] + bs, sa[1] + bs, sa[2] + bs, sa[3] + bs};
            *(floatx4*)&stile[(g * 8 + 7) * 16 + q * 4] = o4;
        }
    }
    __syncthreads();   // stile (all 64 s-channels) + wt_lds (w_out) ready

    // ---- conv_out epilogue: out[b][o][p0+px] = sum_c w_out[o][c]*stile[c][px] + b_out[o]
    {
        int px = tid & 15;
        int oo = tid >> 4;                 // 0..31 -> outputs oo and oo+32
        floatx2 acc; acc.x = b_out[oo]; acc.y = b_out[oo + 32];
        #pragma unroll 8
        for (int c = 0; c < 64; ++c) {
            float sv = stile[c * 16 + px];
            floatx2 w;
            w.x = wt_lds[oo * 65 + c];
            w.y = wt_lds[(oo + 32) * 65 + c];
            floatx2 s2; s2.x = sv; s2.y = sv;
            acc = acc + w * s2;
        }
        out[(b * 64 + oo) * HW + p0 + px]      = acc.x;
        out[(b * 64 + oo + 32) * HW + p0 + px] = acc.y;
    }
}

extern "C" void kernel_launch(void* const* d_in, const int* in_sizes, int n_in,
                              void* d_out, int out_size, void* d_ws, size_t ws_size,
                              hipStream_t stream) {
    const float* h     = (const float*)d_in[0];
    const float* w_in  = (const float*)d_in[1];
    const float* b_in  = (const float*)d_in[2];
    const float* w_ih  = (const float*)d_in[3];
    const float* w_hh  = (const float*)d_in[4];
    const float* b_ih  = (const float*)d_in[5];
    const float* b_hh  = (const float*)d_in[6];
    const float* w_s   = (const float*)d_in[7];
    const float* b_s   = (const float*)d_in[8];
    const float* w_out = (const float*)d_in[9];
    const float* b_out = (const float*)d_in[10];
    float* out = (float*)d_out;
    (void)d_ws; (void)ws_size;

    // single fused kernel: conv_in + LSTM + conv_out. 2048 blocks x 512 threads.
    lstm_kernel<<<2048, 512, 0, stream>>>(h, w_in, b_in, w_ih, w_hh, b_ih, b_hh,
                                          w_s, b_s, w_out, b_out, out);
}